// Round 7
// baseline (69.851 us; speedup 1.0000x reference)
//
#include <hip/hip_runtime.h>

#define B_ROWS   32768
#define NUM_CLS  1000
#define FEAT     512

#define BLOCKS          2048
#define THREADS         256
#define WAVES_PER_BLOCK 4
#define ROWS_PER_WAVE   4      // 2048 * 4 * 4 = 32768

#define CAP 192                // max tracked rows of classes C-2/C-1 (expected ~65)

typedef float f32x4 __attribute__((ext_vector_type(4)));

// ws: [0 .. 2048) per-block intra partials (plain stores, read next dispatch).
// No zeroing needed: every slot is written unconditionally every call.

__global__ __launch_bounds__(THREADS) void loss_pass1(
    const float* __restrict__ features,
    const int*   __restrict__ labels,
    const float* __restrict__ center,
    float*       __restrict__ ws)
{
    const int wave = threadIdx.x >> 6;
    const int lane = threadIdx.x & 63;
    const int wid  = blockIdx.x * WAVES_PER_BLOCK + wave;
    const int base_row = wid * ROWS_PER_WAVE;

    // lanes 0..3 hold this wave's 4 labels
    const int mylab = labels[base_row + (lane & 3)];

    // ---- issue ALL loads first: 16 global_load_dwordx4 in flight per lane ----
    f32x4 f[8], c[8];
    #pragma unroll
    for (int r = 0; r < ROWS_PER_WAVE; ++r) {
        const f32x4* frow = (const f32x4*)(features + (size_t)(base_row + r) * FEAT);
        f[2*r]     = frow[lane];
        f[2*r + 1] = frow[lane + 64];
    }
    #pragma unroll
    for (int r = 0; r < ROWS_PER_WAVE; ++r) {
        const int lab = __shfl(mylab, r);
        const f32x4* crow = (const f32x4*)(center + (size_t)lab * FEAT);
        c[2*r]     = crow[lane];
        c[2*r + 1] = crow[lane + 64];
    }

    float p[ROWS_PER_WAVE];
    #pragma unroll
    for (int r = 0; r < ROWS_PER_WAVE; ++r) {
        f32x4 d0 = f[2*r]     - c[2*r];
        f32x4 d1 = f[2*r + 1] - c[2*r + 1];
        p[r] = d0.x*d0.x + d0.y*d0.y + d0.z*d0.z + d0.w*d0.w
             + d1.x*d1.x + d1.y*d1.y + d1.z*d1.z + d1.w*d1.w;
    }

    // ---- multi-value reduction: 4 row-sums across 64 lanes in 9 shuffles ----
    const bool b0 = lane & 1, b1 = lane & 2;

    float q[2];
    #pragma unroll
    for (int i = 0; i < 2; ++i) {
        float send = b0 ? p[i]     : p[2 + i];
        float keep = b0 ? p[2 + i] : p[i];
        q[i] = keep + __shfl_xor(send, 1);
    }
    float acc;
    {
        float send = b1 ? q[0] : q[1];
        float keep = b1 ? q[1] : q[0];
        float u = keep + __shfl_xor(send, 2);
        u += __shfl_xor(u, 4);
        u += __shfl_xor(u, 8);
        u += __shfl_xor(u, 16);
        u += __shfl_xor(u, 32);
        // each lane in a 4-lane group holds the full sum of a distinct row
        float dist = sqrtf(u);
        dist = fminf(fmaxf(dist, 1e-12f), 1e12f);
        dist += __shfl_xor(dist, 1);
        dist += __shfl_xor(dist, 2);
        acc = dist;   // every lane: sum of this wave's 4 row-distances
    }

    __shared__ float s[WAVES_PER_BLOCK];
    if (lane == 0) s[wave] = acc;
    __syncthreads();
    if (threadIdx.x == 0)
        ws[blockIdx.x] = s[0] + s[1] + s[2] + s[3];   // unique slot, no atomic, no fence
}

__global__ __launch_bounds__(1024) void loss_pass2(
    const float* __restrict__ features,
    const int*   __restrict__ labels,
    const float* __restrict__ center,
    const float* __restrict__ ws,
    float*       __restrict__ out)
{
    const int t    = threadIdx.x;      // 1024 threads, 16 waves
    const int wave = t >> 6;
    const int lane = t & 63;

    __shared__ float sum0[FEAT], sum1[FEAT];
    __shared__ int   list[CAP];
    __shared__ char  clsv[CAP];
    __shared__ int   nmatch, cnt0_s, cnt1_s;

    if (t < FEAT) { sum0[t] = 0.0f; sum1[t] = 0.0f; }
    if (t == 0)   { nmatch = 0; cnt0_s = 0; cnt1_s = 0; }
    __syncthreads();

    // ---- scan all 32768 labels (int4-vectorized, coalesced) ----
    const int4* lab4 = (const int4*)labels;
    #pragma unroll
    for (int k = 0; k < 8; ++k) {
        const int j = t + k * 1024;
        int4 L = lab4[j];
        const int row0 = 4 * j;
        if (L.x >= NUM_CLS - 2) { int i = atomicAdd(&nmatch, 1); if (i < CAP) { list[i] = row0;     clsv[i] = (char)(L.x - (NUM_CLS - 2)); } }
        if (L.y >= NUM_CLS - 2) { int i = atomicAdd(&nmatch, 1); if (i < CAP) { list[i] = row0 + 1; clsv[i] = (char)(L.y - (NUM_CLS - 2)); } }
        if (L.z >= NUM_CLS - 2) { int i = atomicAdd(&nmatch, 1); if (i < CAP) { list[i] = row0 + 2; clsv[i] = (char)(L.z - (NUM_CLS - 2)); } }
        if (L.w >= NUM_CLS - 2) { int i = atomicAdd(&nmatch, 1); if (i < CAP) { list[i] = row0 + 3; clsv[i] = (char)(L.w - (NUM_CLS - 2)); } }
    }
    __syncthreads();

    const int nm = min(nmatch, CAP);

    // per-class counts
    if (t < nm) {
        if (clsv[t] == 0) atomicAdd(&cnt0_s, 1);
        else              atomicAdd(&cnt1_s, 1);
    }

    // ---- gather matched rows: one wave per row, coalesced, accumulate in LDS ----
    for (int i = wave; i < nm; i += 16) {
        const int row = list[i];
        float* dst = clsv[i] ? sum1 : sum0;
        const f32x4* frow = (const f32x4*)(features + (size_t)row * FEAT);
        f32x4 f0 = frow[lane];
        f32x4 f1 = frow[lane + 64];
        const int b = lane * 4;
        atomicAdd(&dst[b + 0],   f0.x);
        atomicAdd(&dst[b + 1],   f0.y);
        atomicAdd(&dst[b + 2],   f0.z);
        atomicAdd(&dst[b + 3],   f0.w);
        atomicAdd(&dst[b + 256], f1.x);
        atomicAdd(&dst[b + 257], f1.y);
        atomicAdd(&dst[b + 258], f1.z);
        atomicAdd(&dst[b + 259], f1.w);
    }
    __syncthreads();

    // ---- inter: 512 dims over threads 0..511 ----
    float p_inter = 0.0f;
    if (t < FEAT) {
        const float cnt0 = fmaxf((float)cnt0_s, 1.0f);
        const float cnt1 = fmaxf((float)cnt1_s, 1.0f);
        float a = (center[(size_t)(NUM_CLS - 2) * FEAT + t] + sum0[t]) / cnt0;
        float b = (center[(size_t)(NUM_CLS - 1) * FEAT + t] + sum1[t]) / cnt1;
        float df = a - b;
        p_inter = df * df;
    }

    // ---- intra: 2048 block partials over 1024 threads ----
    float p_intra = ws[t] + ws[t + 1024];

    #pragma unroll
    for (int off = 32; off; off >>= 1) {
        p_inter += __shfl_xor(p_inter, off);
        p_intra += __shfl_xor(p_intra, off);
    }

    __shared__ float si[16], sa[16];
    if (lane == 0) { si[wave] = p_inter; sa[wave] = p_intra; }
    __syncthreads();

    if (t == 0) {
        float s_inter = 0.0f, s_intra = 0.0f;
        #pragma unroll
        for (int i = 0; i < 16; ++i) { s_inter += si[i]; s_intra += sa[i]; }
        float d_last = sqrtf(s_inter);
        out[0] = s_intra * (1.0f / (float)B_ROWS);
        out[1] = (2.0f / d_last) * (1.0f / ((float)NUM_CLS * (float)(NUM_CLS - 1)));
    }
}

extern "C" void kernel_launch(void* const* d_in, const int* in_sizes, int n_in,
                              void* d_out, int out_size, void* d_ws, size_t ws_size,
                              hipStream_t stream) {
    const float* features = (const float*)d_in[0];
    const int*   labels   = (const int*)d_in[1];
    const float* center   = (const float*)d_in[2];
    float* out = (float*)d_out;
    float* ws  = (float*)d_ws;

    loss_pass1<<<BLOCKS, THREADS, 0, stream>>>(features, labels, center, ws);
    loss_pass2<<<1, 1024, 0, stream>>>(features, labels, center, ws, out);
}

// Round 8
// 25.723 us; speedup vs baseline: 2.7156x; 2.7156x over previous
//
#include <hip/hip_runtime.h>

#define B_ROWS   32768
#define NUM_CLS  1000
#define FEAT     512

#define BLOCKS          2048
#define THREADS         256
#define WAVES_PER_BLOCK 4
#define ROWS_PER_WAVE   4      // 2048 * 4 * 4 = 32768

typedef float f32x4 __attribute__((ext_vector_type(4)));

// ws layout (floats):
//   [1]              count of class C-2
//   [2]              count of class C-1
//   [64 .. 576)      feature sums for class C-2
//   [576 .. 1088)    feature sums for class C-1
//   [1088 .. 3136)   per-block intra partials (plain stores, read next dispatch)
#define WS_CNT0   1
#define WS_CNT1   2
#define WS_SUM0   64
#define WS_SUM1   (64 + 512)
#define WS_PART   (64 + 1024)
#define WS_ZERO_FLOATS (64 + 1024)   // counts + class sums only

__global__ __launch_bounds__(THREADS) void loss_pass1(
    const float* __restrict__ features,
    const int*   __restrict__ labels,
    const float* __restrict__ center,
    float*       __restrict__ ws)
{
    const int wave = threadIdx.x >> 6;
    const int lane = threadIdx.x & 63;
    const int wid  = blockIdx.x * WAVES_PER_BLOCK + wave;
    const int base_row = wid * ROWS_PER_WAVE;

    // lanes 0..3 hold this wave's 4 labels
    const int mylab = labels[base_row + (lane & 3)];

    // ---- issue ALL loads first: 16 global_load_dwordx4 in flight per lane ----
    f32x4 f[8], c[8];
    #pragma unroll
    for (int r = 0; r < ROWS_PER_WAVE; ++r) {
        const f32x4* frow = (const f32x4*)(features + (size_t)(base_row + r) * FEAT);
        f[2*r]     = frow[lane];
        f[2*r + 1] = frow[lane + 64];
    }
    #pragma unroll
    for (int r = 0; r < ROWS_PER_WAVE; ++r) {
        const int lab = __shfl(mylab, r);
        const f32x4* crow = (const f32x4*)(center + (size_t)lab * FEAT);
        c[2*r]     = crow[lane];
        c[2*r + 1] = crow[lane + 64];
    }

    float p[ROWS_PER_WAVE];
    #pragma unroll
    for (int r = 0; r < ROWS_PER_WAVE; ++r) {
        f32x4 d0 = f[2*r]     - c[2*r];
        f32x4 d1 = f[2*r + 1] - c[2*r + 1];
        p[r] = d0.x*d0.x + d0.y*d0.y + d0.z*d0.z + d0.w*d0.w
             + d1.x*d1.x + d1.y*d1.y + d1.z*d1.z + d1.w*d1.w;
    }

    // Inter-loss bookkeeping: classes C-2/C-1 only (~65 of 32768 rows)
    #pragma unroll
    for (int r = 0; r < ROWS_PER_WAVE; ++r) {
        const int lab = __shfl(mylab, r);
        if (lab >= NUM_CLS - 2) {
            float* sums = ws + (lab == NUM_CLS - 2 ? WS_SUM0 : WS_SUM1);
            const int base = lane * 4;
            f32x4 f0 = f[2*r], f1 = f[2*r + 1];
            atomicAdd(&sums[base + 0],   f0.x);
            atomicAdd(&sums[base + 1],   f0.y);
            atomicAdd(&sums[base + 2],   f0.z);
            atomicAdd(&sums[base + 3],   f0.w);
            atomicAdd(&sums[base + 256], f1.x);
            atomicAdd(&sums[base + 257], f1.y);
            atomicAdd(&sums[base + 258], f1.z);
            atomicAdd(&sums[base + 259], f1.w);
            if (lane == 0)
                atomicAdd(&ws[lab == NUM_CLS - 2 ? WS_CNT0 : WS_CNT1], 1.0f);
        }
    }

    // ---- multi-value reduction: 4 row-sums across 64 lanes in 9 shuffles ----
    const bool b0 = lane & 1, b1 = lane & 2;

    float q[2];
    #pragma unroll
    for (int i = 0; i < 2; ++i) {
        float send = b0 ? p[i]     : p[2 + i];
        float keep = b0 ? p[2 + i] : p[i];
        q[i] = keep + __shfl_xor(send, 1);
    }
    float acc;
    {
        float send = b1 ? q[0] : q[1];
        float keep = b1 ? q[1] : q[0];
        float u = keep + __shfl_xor(send, 2);
        u += __shfl_xor(u, 4);
        u += __shfl_xor(u, 8);
        u += __shfl_xor(u, 16);
        u += __shfl_xor(u, 32);
        // each lane in a 4-lane group holds the full sum of a distinct row
        float dist = sqrtf(u);
        dist = fminf(fmaxf(dist, 1e-12f), 1e12f);
        dist += __shfl_xor(dist, 1);
        dist += __shfl_xor(dist, 2);
        acc = dist;   // every lane: sum of this wave's 4 row-distances
    }

    __shared__ float s[WAVES_PER_BLOCK];
    if (lane == 0) s[wave] = acc;
    __syncthreads();
    if (threadIdx.x == 0)
        ws[WS_PART + blockIdx.x] = s[0] + s[1] + s[2] + s[3];  // unique slot, no atomic, no fence
}

__global__ __launch_bounds__(256) void loss_pass2(
    const float* __restrict__ center,
    const float* __restrict__ ws,
    float*       __restrict__ out)
{
    const int t = threadIdx.x;
    const float cnt0 = fmaxf(ws[WS_CNT0], 1.0f);
    const float cnt1 = fmaxf(ws[WS_CNT1], 1.0f);

    // inter: 512 dims over 256 threads (2 each)
    float p_inter = 0.0f;
    #pragma unroll
    for (int k = 0; k < 2; ++k) {
        const int d = t * 2 + k;
        float a = (center[(size_t)(NUM_CLS - 2) * FEAT + d] + ws[WS_SUM0 + d]) / cnt0;
        float b = (center[(size_t)(NUM_CLS - 1) * FEAT + d] + ws[WS_SUM1 + d]) / cnt1;
        float df = a - b;
        p_inter += df * df;
    }

    // intra: 2048 block partials over 256 threads, f32x4-vectorized (2 per thread)
    const f32x4* part4 = (const f32x4*)(ws + WS_PART);
    f32x4 v0 = part4[t];
    f32x4 v1 = part4[t + 256];
    float p_intra = (v0.x + v0.y + v0.z + v0.w) + (v1.x + v1.y + v1.z + v1.w);

    #pragma unroll
    for (int off = 32; off; off >>= 1) {
        p_inter += __shfl_xor(p_inter, off);
        p_intra += __shfl_xor(p_intra, off);
    }

    __shared__ float si[4], sa[4];
    if ((t & 63) == 0) { si[t >> 6] = p_inter; sa[t >> 6] = p_intra; }
    __syncthreads();

    if (t == 0) {
        float d_last = sqrtf(si[0] + si[1] + si[2] + si[3]);
        out[0] = (sa[0] + sa[1] + sa[2] + sa[3]) * (1.0f / (float)B_ROWS);
        out[1] = (2.0f / d_last) * (1.0f / ((float)NUM_CLS * (float)(NUM_CLS - 1)));
    }
}

extern "C" void kernel_launch(void* const* d_in, const int* in_sizes, int n_in,
                              void* d_out, int out_size, void* d_ws, size_t ws_size,
                              hipStream_t stream) {
    const float* features = (const float*)d_in[0];
    const int*   labels   = (const int*)d_in[1];
    const float* center   = (const float*)d_in[2];
    float* out = (float*)d_out;
    float* ws  = (float*)d_ws;

    (void)hipMemsetAsync(ws, 0, WS_ZERO_FLOATS * sizeof(float), stream);

    loss_pass1<<<BLOCKS, THREADS, 0, stream>>>(features, labels, center, ws);
    loss_pass2<<<1, 256, 0, stream>>>(center, ws, out);
}

// Round 9
// 25.418 us; speedup vs baseline: 2.7481x; 1.0120x over previous
//
#include <hip/hip_runtime.h>

#define B_ROWS   32768
#define NUM_CLS  1000
#define FEAT     512

#define BLOCKS          4096
#define THREADS         256
#define WAVES_PER_BLOCK 4
#define ROWS_PER_WAVE   2      // 4096 * 4 * 2 = 32768

typedef float f32x4 __attribute__((ext_vector_type(4)));

// ws layout (floats):
//   [1]              count of class C-2
//   [2]              count of class C-1
//   [64 .. 576)      feature sums for class C-2
//   [576 .. 1088)    feature sums for class C-1
//   [1088 .. 5184)   per-block intra partials (plain stores, read next dispatch)
#define WS_CNT0   1
#define WS_CNT1   2
#define WS_SUM0   64
#define WS_SUM1   (64 + 512)
#define WS_PART   (64 + 1024)
#define WS_ZERO_FLOATS (64 + 1024)   // counts + class sums only

__global__ __launch_bounds__(THREADS) void loss_pass1(
    const float* __restrict__ features,
    const int*   __restrict__ labels,
    const float* __restrict__ center,
    float*       __restrict__ ws)
{
    const int wave = threadIdx.x >> 6;
    const int lane = threadIdx.x & 63;
    const int wid  = blockIdx.x * WAVES_PER_BLOCK + wave;
    const int base_row = wid * ROWS_PER_WAVE;

    // lanes 0..1 hold this wave's 2 labels
    const int mylab = labels[base_row + (lane & 1)];

    // ---- issue all loads up front: 8 dwordx4 per lane in flight ----
    f32x4 f[4], c[4];
    #pragma unroll
    for (int r = 0; r < ROWS_PER_WAVE; ++r) {
        const f32x4* frow = (const f32x4*)(features + (size_t)(base_row + r) * FEAT);
        f[2*r]     = frow[lane];
        f[2*r + 1] = frow[lane + 64];
    }
    #pragma unroll
    for (int r = 0; r < ROWS_PER_WAVE; ++r) {
        const int lab = __shfl(mylab, r);
        const f32x4* crow = (const f32x4*)(center + (size_t)lab * FEAT);
        c[2*r]     = crow[lane];
        c[2*r + 1] = crow[lane + 64];
    }

    float p[ROWS_PER_WAVE];
    #pragma unroll
    for (int r = 0; r < ROWS_PER_WAVE; ++r) {
        f32x4 d0 = f[2*r]     - c[2*r];
        f32x4 d1 = f[2*r + 1] - c[2*r + 1];
        p[r] = d0.x*d0.x + d0.y*d0.y + d0.z*d0.z + d0.w*d0.w
             + d1.x*d1.x + d1.y*d1.y + d1.z*d1.z + d1.w*d1.w;
    }

    // Inter-loss bookkeeping: classes C-2/C-1 only (~65 of 32768 rows)
    #pragma unroll
    for (int r = 0; r < ROWS_PER_WAVE; ++r) {
        const int lab = __shfl(mylab, r);
        if (lab >= NUM_CLS - 2) {
            float* sums = ws + (lab == NUM_CLS - 2 ? WS_SUM0 : WS_SUM1);
            const int base = lane * 4;
            f32x4 f0 = f[2*r], f1 = f[2*r + 1];
            atomicAdd(&sums[base + 0],   f0.x);
            atomicAdd(&sums[base + 1],   f0.y);
            atomicAdd(&sums[base + 2],   f0.z);
            atomicAdd(&sums[base + 3],   f0.w);
            atomicAdd(&sums[base + 256], f1.x);
            atomicAdd(&sums[base + 257], f1.y);
            atomicAdd(&sums[base + 258], f1.z);
            atomicAdd(&sums[base + 259], f1.w);
            if (lane == 0)
                atomicAdd(&ws[lab == NUM_CLS - 2 ? WS_CNT0 : WS_CNT1], 1.0f);
        }
    }

    // ---- multi-value reduction: 2 row-sums across 64 lanes in 7 shuffles ----
    const bool b0 = lane & 1;
    float send = b0 ? p[0] : p[1];
    float keep = b0 ? p[1] : p[0];
    float u = keep + __shfl_xor(send, 1);   // lane parity owns one row's partial
    u += __shfl_xor(u, 2);
    u += __shfl_xor(u, 4);
    u += __shfl_xor(u, 8);
    u += __shfl_xor(u, 16);
    u += __shfl_xor(u, 32);
    // each lane in a 2-lane pair holds the full sum of a distinct row
    float dist = sqrtf(u);
    dist = fminf(fmaxf(dist, 1e-12f), 1e12f);
    dist += __shfl_xor(dist, 1);            // sum the 2 rows
    const float acc = dist;                 // every lane: this wave's 2-row distance sum

    __shared__ float s[WAVES_PER_BLOCK];
    if (lane == 0) s[wave] = acc;
    __syncthreads();
    if (threadIdx.x == 0)
        ws[WS_PART + blockIdx.x] = s[0] + s[1] + s[2] + s[3];  // unique slot, no atomic, no fence
}

__global__ __launch_bounds__(256) void loss_pass2(
    const float* __restrict__ center,
    const float* __restrict__ ws,
    float*       __restrict__ out)
{
    const int t = threadIdx.x;
    const float cnt0 = fmaxf(ws[WS_CNT0], 1.0f);
    const float cnt1 = fmaxf(ws[WS_CNT1], 1.0f);

    // inter: 512 dims over 256 threads (2 each)
    float p_inter = 0.0f;
    #pragma unroll
    for (int k = 0; k < 2; ++k) {
        const int d = t * 2 + k;
        float a = (center[(size_t)(NUM_CLS - 2) * FEAT + d] + ws[WS_SUM0 + d]) / cnt0;
        float b = (center[(size_t)(NUM_CLS - 1) * FEAT + d] + ws[WS_SUM1 + d]) / cnt1;
        float df = a - b;
        p_inter += df * df;
    }

    // intra: 4096 block partials over 256 threads, f32x4-vectorized (4 per thread)
    const f32x4* part4 = (const f32x4*)(ws + WS_PART);
    float p_intra = 0.0f;
    #pragma unroll
    for (int k = 0; k < 4; ++k) {
        f32x4 v = part4[t + k * 256];
        p_intra += (v.x + v.y) + (v.z + v.w);
    }

    #pragma unroll
    for (int off = 32; off; off >>= 1) {
        p_inter += __shfl_xor(p_inter, off);
        p_intra += __shfl_xor(p_intra, off);
    }

    __shared__ float si[4], sa[4];
    if ((t & 63) == 0) { si[t >> 6] = p_inter; sa[t >> 6] = p_intra; }
    __syncthreads();

    if (t == 0) {
        float d_last = sqrtf(si[0] + si[1] + si[2] + si[3]);
        out[0] = (sa[0] + sa[1] + sa[2] + sa[3]) * (1.0f / (float)B_ROWS);
        out[1] = (2.0f / d_last) * (1.0f / ((float)NUM_CLS * (float)(NUM_CLS - 1)));
    }
}

extern "C" void kernel_launch(void* const* d_in, const int* in_sizes, int n_in,
                              void* d_out, int out_size, void* d_ws, size_t ws_size,
                              hipStream_t stream) {
    const float* features = (const float*)d_in[0];
    const int*   labels   = (const int*)d_in[1];
    const float* center   = (const float*)d_in[2];
    float* out = (float*)d_out;
    float* ws  = (float*)d_ws;

    (void)hipMemsetAsync(ws, 0, WS_ZERO_FLOATS * sizeof(float), stream);

    loss_pass1<<<BLOCKS, THREADS, 0, stream>>>(features, labels, center, ws);
    loss_pass2<<<1, 256, 0, stream>>>(center, ws, out);
}

// Round 10
// 21.692 us; speedup vs baseline: 3.2202x; 1.1718x over previous
//
#include <hip/hip_runtime.h>

#define B_ROWS   32768
#define NUM_CLS  1000
#define FEAT     512

#define INTER_BLOCKS    16
#define INTRA_BLOCKS    4096
#define THREADS         256
#define WAVES_PER_BLOCK 4
#define ROWS_PER_WAVE   2      // 4096 * 4 * 2 = 32768
#define LABELS_PER_IB   (B_ROWS / INTER_BLOCKS)   // 2048
#define LISTCAP         128

typedef float f32x4 __attribute__((ext_vector_type(4)));
typedef float f32x2 __attribute__((ext_vector_type(2)));

// ws layout (floats) — every slot written unconditionally every call, no zeroing:
//   [0 .. 4096)                 intra per-block partials
//   [4096 .. 4096+16*1032)      inter per-block slots:
//       slot+0 = cnt0, slot+1 = cnt1, slot+[2..514) = sum0, slot+[514..1026) = sum1
#define WS_INTER 4096
#define SLOT     1032

__global__ __launch_bounds__(THREADS) void loss_pass1(
    const float* __restrict__ features,
    const int*   __restrict__ labels,
    const float* __restrict__ center,
    float*       __restrict__ ws)
{
    if (blockIdx.x < INTER_BLOCKS) {
        // ================= inter blocks: class C-2/C-1 partial sums =================
        const int ib = blockIdx.x;
        const int t  = threadIdx.x;

        __shared__ int list[LISTCAP];
        __shared__ int nm_s;
        if (t == 0) nm_s = 0;
        __syncthreads();

        // scan 2048 labels: 512 int4, 2 per thread, coalesced
        const int4* lab4 = (const int4*)(labels + ib * LABELS_PER_IB);
        #pragma unroll
        for (int k = 0; k < 2; ++k) {
            const int j = t + k * 256;
            int4 L = lab4[j];
            const int row0 = ib * LABELS_PER_IB + 4 * j;
            if (L.x >= NUM_CLS - 2) { int i = atomicAdd(&nm_s, 1); if (i < LISTCAP) list[i] = (row0 << 1)       | (L.x - (NUM_CLS - 2)); }
            if (L.y >= NUM_CLS - 2) { int i = atomicAdd(&nm_s, 1); if (i < LISTCAP) list[i] = ((row0 + 1) << 1) | (L.y - (NUM_CLS - 2)); }
            if (L.z >= NUM_CLS - 2) { int i = atomicAdd(&nm_s, 1); if (i < LISTCAP) list[i] = ((row0 + 2) << 1) | (L.z - (NUM_CLS - 2)); }
            if (L.w >= NUM_CLS - 2) { int i = atomicAdd(&nm_s, 1); if (i < LISTCAP) list[i] = ((row0 + 3) << 1) | (L.w - (NUM_CLS - 2)); }
        }
        __syncthreads();
        const int nm = min(nm_s, LISTCAP);

        // accumulate matched rows in registers: thread t owns dims 2t, 2t+1
        float s0a = 0.0f, s0b = 0.0f, s1a = 0.0f, s1b = 0.0f;
        int c0 = 0, c1 = 0;
        for (int m = 0; m < nm; ++m) {
            const int e   = list[m];
            const int row = e >> 1;
            const f32x2 v = ((const f32x2*)(features + (size_t)row * FEAT))[t];
            if (e & 1) { s1a += v.x; s1b += v.y; ++c1; }
            else       { s0a += v.x; s0b += v.y; ++c0; }
        }

        float* slot = ws + WS_INTER + ib * SLOT;
        if (t == 0) { slot[0] = (float)c0; slot[1] = (float)c1; }
        f32x2 v0; v0.x = s0a; v0.y = s0b;
        f32x2 v1; v1.x = s1a; v1.y = s1b;
        ((f32x2*)(slot + 2))[t]   = v0;
        ((f32x2*)(slot + 514))[t] = v1;
        return;
    }

    // ================= intra blocks: streaming distance reduce =================
    const int bid  = blockIdx.x - INTER_BLOCKS;
    const int wave = threadIdx.x >> 6;
    const int lane = threadIdx.x & 63;
    const int wid  = bid * WAVES_PER_BLOCK + wave;
    const int base_row = wid * ROWS_PER_WAVE;

    const int mylab = labels[base_row + (lane & 1)];

    f32x4 f[4], c[4];
    #pragma unroll
    for (int r = 0; r < ROWS_PER_WAVE; ++r) {
        const f32x4* frow = (const f32x4*)(features + (size_t)(base_row + r) * FEAT);
        f[2*r]     = frow[lane];
        f[2*r + 1] = frow[lane + 64];
    }
    #pragma unroll
    for (int r = 0; r < ROWS_PER_WAVE; ++r) {
        const int lab = __shfl(mylab, r);
        const f32x4* crow = (const f32x4*)(center + (size_t)lab * FEAT);
        c[2*r]     = crow[lane];
        c[2*r + 1] = crow[lane + 64];
    }

    float p[ROWS_PER_WAVE];
    #pragma unroll
    for (int r = 0; r < ROWS_PER_WAVE; ++r) {
        f32x4 d0 = f[2*r]     - c[2*r];
        f32x4 d1 = f[2*r + 1] - c[2*r + 1];
        p[r] = d0.x*d0.x + d0.y*d0.y + d0.z*d0.z + d0.w*d0.w
             + d1.x*d1.x + d1.y*d1.y + d1.z*d1.z + d1.w*d1.w;
    }

    // 2 row-sums across 64 lanes in 7 shuffles
    const bool b0 = lane & 1;
    float send = b0 ? p[0] : p[1];
    float keep = b0 ? p[1] : p[0];
    float u = keep + __shfl_xor(send, 1);
    u += __shfl_xor(u, 2);
    u += __shfl_xor(u, 4);
    u += __shfl_xor(u, 8);
    u += __shfl_xor(u, 16);
    u += __shfl_xor(u, 32);
    float dist = sqrtf(u);
    dist = fminf(fmaxf(dist, 1e-12f), 1e12f);
    dist += __shfl_xor(dist, 1);

    __shared__ float s[WAVES_PER_BLOCK];
    if (lane == 0) s[wave] = dist;
    __syncthreads();
    if (threadIdx.x == 0)
        ws[bid] = s[0] + s[1] + s[2] + s[3];   // unique slot, no atomic, no fence
}

__global__ __launch_bounds__(256) void loss_pass2(
    const float* __restrict__ center,
    const float* __restrict__ ws,
    float*       __restrict__ out)
{
    const int t = threadIdx.x;

    // counts (uniform address per iteration -> broadcast loads)
    float cnt0 = 0.0f, cnt1 = 0.0f;
    #pragma unroll
    for (int b = 0; b < INTER_BLOCKS; ++b) {
        const float* slot = ws + WS_INTER + b * SLOT;
        cnt0 += slot[0];
        cnt1 += slot[1];
    }
    cnt0 = fmaxf(cnt0, 1.0f);
    cnt1 = fmaxf(cnt1, 1.0f);

    // class sums: thread t owns dims 2t, 2t+1
    float s0a = 0.0f, s0b = 0.0f, s1a = 0.0f, s1b = 0.0f;
    #pragma unroll
    for (int b = 0; b < INTER_BLOCKS; ++b) {
        const float* slot = ws + WS_INTER + b * SLOT;
        f32x2 v0 = ((const f32x2*)(slot + 2))[t];
        f32x2 v1 = ((const f32x2*)(slot + 514))[t];
        s0a += v0.x; s0b += v0.y;
        s1a += v1.x; s1b += v1.y;
    }

    const int d = 2 * t;
    float a0 = (center[(size_t)(NUM_CLS - 2) * FEAT + d]     + s0a) / cnt0;
    float b0 = (center[(size_t)(NUM_CLS - 1) * FEAT + d]     + s1a) / cnt1;
    float a1 = (center[(size_t)(NUM_CLS - 2) * FEAT + d + 1] + s0b) / cnt0;
    float b1 = (center[(size_t)(NUM_CLS - 1) * FEAT + d + 1] + s1b) / cnt1;
    float df0 = a0 - b0, df1 = a1 - b1;
    float p_inter = df0 * df0 + df1 * df1;

    // intra: 4096 block partials, f32x4 x 4 per thread
    const f32x4* part4 = (const f32x4*)ws;
    float p_intra = 0.0f;
    #pragma unroll
    for (int k = 0; k < 4; ++k) {
        f32x4 v = part4[t + k * 256];
        p_intra += (v.x + v.y) + (v.z + v.w);
    }

    #pragma unroll
    for (int off = 32; off; off >>= 1) {
        p_inter += __shfl_xor(p_inter, off);
        p_intra += __shfl_xor(p_intra, off);
    }

    __shared__ float si[4], sa[4];
    if ((t & 63) == 0) { si[t >> 6] = p_inter; sa[t >> 6] = p_intra; }
    __syncthreads();

    if (t == 0) {
        float d_last = sqrtf(si[0] + si[1] + si[2] + si[3]);
        out[0] = (sa[0] + sa[1] + sa[2] + sa[3]) * (1.0f / (float)B_ROWS);
        out[1] = (2.0f / d_last) * (1.0f / ((float)NUM_CLS * (float)(NUM_CLS - 1)));
    }
}

extern "C" void kernel_launch(void* const* d_in, const int* in_sizes, int n_in,
                              void* d_out, int out_size, void* d_ws, size_t ws_size,
                              hipStream_t stream) {
    const float* features = (const float*)d_in[0];
    const int*   labels   = (const int*)d_in[1];
    const float* center   = (const float*)d_in[2];
    float* out = (float*)d_out;
    float* ws  = (float*)d_ws;

    loss_pass1<<<INTER_BLOCKS + INTRA_BLOCKS, THREADS, 0, stream>>>(features, labels, center, ws);
    loss_pass2<<<1, 256, 0, stream>>>(center, ws, out);
}

// Round 11
// 21.510 us; speedup vs baseline: 3.2473x; 1.0084x over previous
//
#include <hip/hip_runtime.h>

#define B_ROWS   32768
#define NUM_CLS  1000
#define FEAT     512

#define INTER_BLOCKS    16
#define INTRA_BLOCKS    4096
#define THREADS         256
#define WAVES_PER_BLOCK 4
#define ROWS_PER_WAVE   2      // 4096 * 4 * 2 = 32768
#define TOTAL_WAVES     (INTRA_BLOCKS * WAVES_PER_BLOCK)   // 16384
#define LABELS_PER_IB   (B_ROWS / INTER_BLOCKS)   // 2048
#define LISTCAP         128

typedef float f32x4 __attribute__((ext_vector_type(4)));
typedef float f32x2 __attribute__((ext_vector_type(2)));

// ws layout (floats) — every slot written unconditionally every call, no zeroing:
//   [0 .. 16384)                per-WAVE intra partials
//   [16384 .. 16384+16*1032)    inter per-block slots:
//       slot+0 = cnt0, slot+1 = cnt1, slot+[2..514) = sum0, slot+[514..1026) = sum1
#define WS_INTER 16384
#define SLOT     1032

__global__ __launch_bounds__(THREADS, 8) void loss_pass1(
    const float* __restrict__ features,
    const int*   __restrict__ labels,
    const float* __restrict__ center,
    float*       __restrict__ ws)
{
    if (blockIdx.x < INTER_BLOCKS) {
        // ================= inter blocks: class C-2/C-1 partial sums =================
        const int ib = blockIdx.x;
        const int t  = threadIdx.x;

        __shared__ int list[LISTCAP];
        __shared__ int nm_s;
        if (t == 0) nm_s = 0;
        __syncthreads();

        const int4* lab4 = (const int4*)(labels + ib * LABELS_PER_IB);
        #pragma unroll
        for (int k = 0; k < 2; ++k) {
            const int j = t + k * 256;
            int4 L = lab4[j];
            const int row0 = ib * LABELS_PER_IB + 4 * j;
            if (L.x >= NUM_CLS - 2) { int i = atomicAdd(&nm_s, 1); if (i < LISTCAP) list[i] = (row0 << 1)       | (L.x - (NUM_CLS - 2)); }
            if (L.y >= NUM_CLS - 2) { int i = atomicAdd(&nm_s, 1); if (i < LISTCAP) list[i] = ((row0 + 1) << 1) | (L.y - (NUM_CLS - 2)); }
            if (L.z >= NUM_CLS - 2) { int i = atomicAdd(&nm_s, 1); if (i < LISTCAP) list[i] = ((row0 + 2) << 1) | (L.z - (NUM_CLS - 2)); }
            if (L.w >= NUM_CLS - 2) { int i = atomicAdd(&nm_s, 1); if (i < LISTCAP) list[i] = ((row0 + 3) << 1) | (L.w - (NUM_CLS - 2)); }
        }
        __syncthreads();
        const int nm = min(nm_s, LISTCAP);

        float s0a = 0.0f, s0b = 0.0f, s1a = 0.0f, s1b = 0.0f;
        int c0 = 0, c1 = 0;
        for (int m = 0; m < nm; ++m) {
            const int e   = list[m];
            const int row = e >> 1;
            const f32x2 v = ((const f32x2*)(features + (size_t)row * FEAT))[t];
            if (e & 1) { s1a += v.x; s1b += v.y; ++c1; }
            else       { s0a += v.x; s0b += v.y; ++c0; }
        }

        float* slot = ws + WS_INTER + ib * SLOT;
        if (t == 0) { slot[0] = (float)c0; slot[1] = (float)c1; }
        f32x2 v0; v0.x = s0a; v0.y = s0b;
        f32x2 v1; v1.x = s1a; v1.y = s1b;
        ((f32x2*)(slot + 2))[t]   = v0;
        ((f32x2*)(slot + 514))[t] = v1;
        return;
    }

    // ================= intra blocks: streaming distance reduce =================
    const int bid  = blockIdx.x - INTER_BLOCKS;
    const int lane = threadIdx.x & 63;
    // wave id, forced wave-uniform into an SGPR
    const int wave = __builtin_amdgcn_readfirstlane(threadIdx.x >> 6);
    const int wid  = bid * WAVES_PER_BLOCK + wave;
    const int base_row = wid * ROWS_PER_WAVE;

    // wave-uniform scalar label loads (SMEM path, no vector round-trip + shfl)
    const int lab0 = labels[base_row];
    const int lab1 = labels[base_row + 1];

    const f32x4* f0p = (const f32x4*)(features + (size_t)base_row * FEAT);
    const f32x4* f1p = (const f32x4*)(features + (size_t)(base_row + 1) * FEAT);
    const f32x4* c0p = (const f32x4*)(center   + (size_t)lab0 * FEAT);
    const f32x4* c1p = (const f32x4*)(center   + (size_t)lab1 * FEAT);

    f32x4 fa = f0p[lane];
    f32x4 fb = f0p[lane + 64];
    f32x4 fc = f1p[lane];
    f32x4 fd = f1p[lane + 64];
    f32x4 ca = c0p[lane];
    f32x4 cb = c0p[lane + 64];
    f32x4 cc = c1p[lane];
    f32x4 cd = c1p[lane + 64];

    f32x4 d0 = fa - ca, d1 = fb - cb, d2 = fc - cc, d3 = fd - cd;
    float p0 = d0.x*d0.x + d0.y*d0.y + d0.z*d0.z + d0.w*d0.w
             + d1.x*d1.x + d1.y*d1.y + d1.z*d1.z + d1.w*d1.w;
    float p1 = d2.x*d2.x + d2.y*d2.y + d2.z*d2.z + d2.w*d2.w
             + d3.x*d3.x + d3.y*d3.y + d3.z*d3.z + d3.w*d3.w;

    // 2 row-sums across 64 lanes in 7 shuffles
    const bool b0 = lane & 1;
    float send = b0 ? p0 : p1;
    float keep = b0 ? p1 : p0;
    float u = keep + __shfl_xor(send, 1);
    u += __shfl_xor(u, 2);
    u += __shfl_xor(u, 4);
    u += __shfl_xor(u, 8);
    u += __shfl_xor(u, 16);
    u += __shfl_xor(u, 32);
    float dist = sqrtf(u);
    dist = fminf(fmaxf(dist, 1e-12f), 1e12f);
    dist += __shfl_xor(dist, 1);            // sum the 2 rows

    if (lane == 0)
        ws[wid] = dist;    // unique per-wave slot: no LDS, no barrier, no atomic
}

__global__ __launch_bounds__(512) void loss_pass2(
    const float* __restrict__ center,
    const float* __restrict__ ws,
    float*       __restrict__ out)
{
    const int t = threadIdx.x;     // 512 threads, 8 waves

    // counts (wave-uniform broadcast loads)
    float cnt0 = 0.0f, cnt1 = 0.0f;
    #pragma unroll
    for (int b = 0; b < INTER_BLOCKS; ++b) {
        const float* slot = ws + WS_INTER + b * SLOT;
        cnt0 += slot[0];
        cnt1 += slot[1];
    }
    cnt0 = fmaxf(cnt0, 1.0f);
    cnt1 = fmaxf(cnt1, 1.0f);

    // class sums: thread t owns dim t
    float s0 = 0.0f, s1 = 0.0f;
    #pragma unroll
    for (int b = 0; b < INTER_BLOCKS; ++b) {
        const float* slot = ws + WS_INTER + b * SLOT;
        s0 += slot[2 + t];
        s1 += slot[514 + t];
    }

    float a  = (center[(size_t)(NUM_CLS - 2) * FEAT + t] + s0) / cnt0;
    float bb = (center[(size_t)(NUM_CLS - 1) * FEAT + t] + s1) / cnt1;
    float df = a - bb;
    float p_inter = df * df;

    // intra: 16384 wave partials, f32x4 x 8 per thread
    const f32x4* part4 = (const f32x4*)ws;
    float p_intra = 0.0f;
    #pragma unroll
    for (int k = 0; k < 8; ++k) {
        f32x4 v = part4[t + k * 512];
        p_intra += (v.x + v.y) + (v.z + v.w);
    }

    #pragma unroll
    for (int off = 32; off; off >>= 1) {
        p_inter += __shfl_xor(p_inter, off);
        p_intra += __shfl_xor(p_intra, off);
    }

    __shared__ float si[8], sa[8];
    if ((t & 63) == 0) { si[t >> 6] = p_inter; sa[t >> 6] = p_intra; }
    __syncthreads();

    if (t == 0) {
        float s_inter = 0.0f, s_intra = 0.0f;
        #pragma unroll
        for (int i = 0; i < 8; ++i) { s_inter += si[i]; s_intra += sa[i]; }
        float d_last = sqrtf(s_inter);
        out[0] = s_intra * (1.0f / (float)B_ROWS);
        out[1] = (2.0f / d_last) * (1.0f / ((float)NUM_CLS * (float)(NUM_CLS - 1)));
    }
}

extern "C" void kernel_launch(void* const* d_in, const int* in_sizes, int n_in,
                              void* d_out, int out_size, void* d_ws, size_t ws_size,
                              hipStream_t stream) {
    const float* features = (const float*)d_in[0];
    const int*   labels   = (const int*)d_in[1];
    const float* center   = (const float*)d_in[2];
    float* out = (float*)d_out;
    float* ws  = (float*)d_ws;

    loss_pass1<<<INTER_BLOCKS + INTRA_BLOCKS, THREADS, 0, stream>>>(features, labels, center, ws);
    loss_pass2<<<1, 512, 0, stream>>>(center, ws, out);
}